// Round 14
// baseline (179.176 us; speedup 1.0000x reference)
//
#include <hip/hip_runtime.h>
#include <hip/hip_bf16.h>

// 2D-MDLSTM (4 directions) + FC head for MI355X — round 14.
//
// R13 post-mortem: dual-tile ILP interleave regressed (85.0 vs R12 83.1) —
// the 2 waves/SIMD already interleave the two tiles; span model was wrong.
// All latency-structure levers (R5/R6-8/R10/R13) are exhausted; R12 is the
// plateau mdlstm. Bank conflicts (6.24M, byte-identical across paddings)
// are structural b128 phase-aliasing — not fixable.
//
// R14: attack the last removable chunk — the fc dispatch + launch gap:
//  1. fc FUSED into mdlstm's tail: the 4 dir-WGs of a batch-pair atomicOr
//     bits 0/2/4/6 (all clear under 0xAA poison -> no init, any-base
//     robust) into a d_ws counter after __threadfence; the 4th arriver
//     runs the FC head for its 2 rows in-kernel. Fallback to separate fc
//     if ws_size too small (host-side check, constant per harness).
//  2. MFMA chain split: per gate 2 independent chains (ks{4,0,1},{2,3}) +
//     f32x4 add -> dependency depth 5 -> 3.
// Carried from R12: c-preload before MFMAs, merged trans + cn<=22 clamp,
// x*Wx+b as 5th K-step, exp2-folded gate scales, t-loop x2 unroll,
// branchless clamped epilogue, S_H=104/S_C=68.

#define GRIDN 28
#define BATCH 128
#define HID   64
#define NDIR  4
#define FC_HD 512
#define OUT_N 10
#define BT    2
#define NTHR  512
#define NSLOT 29          // 28 frontier rows + permanent-zero row (r = -1)
#define S_H   104         // f16/slot: [0,64) h | [64]=x [65]=1 [66,96)=0 | 8 pad
#define S_C   68          // float/slot: 64 c + 4 pad

typedef _Float16 f16;
typedef _Float16 f16x8 __attribute__((ext_vector_type(8)));
typedef float    f32x4 __attribute__((ext_vector_type(4)));

#define LOG2E  1.44269504088896340736f
#define LOG2E2 2.88539008177792681472f

__device__ __forceinline__ float rcpf(float x) { return __builtin_amdgcn_rcpf(x); }
__device__ __forceinline__ float ex2(float x)  { return __builtin_amdgcn_exp2f(x); }

__global__ __launch_bounds__(NTHR)
void mdlstm_kernel(const float* __restrict__ x,    // [B][28][28]
                   const float* __restrict__ Wx,   // [4][320]
                   const float* __restrict__ U,    // [4][128][320]
                   const float* __restrict__ bias, // [4][320]
                   float* __restrict__ Hout,       // [4][B][64] (d_ws)
                   const float* __restrict__ W1, const float* __restrict__ b1,
                   const float* __restrict__ W2, const float* __restrict__ b2,
                   float* __restrict__ out,        // [B][10]
                   unsigned* __restrict__ cnt,     // [64] completion bits (d_ws)
                   int fused)
{
    const int d    = blockIdx.x & 3;
    const int tile = blockIdx.x >> 2;     // 0..63 batch-pair
    const int tid  = threadIdx.x;
    const int lane = tid & 63;
    const int wave = tid >> 6;            // 0..7
    const int wm   = wave >> 2;           // tile parity 0/1
    const int wh   = wave & 3;            // h-subtile (n = wh*16 + l16)
    const int l16  = lane & 15;
    const int q    = lane >> 4;
    const int nb   = wh * 16 + l16;       // this lane's h index 0..63

    __shared__ __align__(16) f16 Fh[2][BT][NSLOT * S_H];
    __shared__ float             Fc[2][BT][NSLOT * S_C];
    __shared__ float             xs[GRIDN][GRIDN][BT];
    // fc-tail scratch (winner WG only; ~10 KB, total LDS ~72 KB < 80)
    __shared__ float             hrow2[2][NDIR * HID];
    __shared__ float             z1b[2][FC_HD];
    __shared__ float             ps2[2][32][16];
    __shared__ float             z2b[2][16];
    __shared__ int               fcflag;

    for (int i = tid; i < 2 * BT * NSLOT * S_H; i += NTHR) ((f16*)Fh)[i] = (f16)0.0f;
    for (int i = tid; i < 2 * BT * NSLOT * S_C; i += NTHR) ((float*)Fc)[i] = 0.0f;
    for (int i = tid; i < GRIDN * GRIDN * BT; i += NTHR) {
        int bl = i & 1, rc = i >> 1, c = rc % GRIDN, r = rc / GRIDN;
        int rr = (d & 2) ? (GRIDN - 1 - r) : r;
        int cc = (d & 1) ? (GRIDN - 1 - c) : c;
        xs[r][c][bl] = x[((tile * BT + bl) * GRIDN + rr) * GRIDN + cc];
    }

    // ---- B-fragments in registers, gate-scaled: 25 x f16x8 (100 regs)
    // sigmoid gates scaled by -log2e (sig = rcp(1+2^acc)); g gate by +2log2e.
    f16x8 bf[5][5];
#pragma unroll
    for (int g = 0; g < 5; ++g) {
        const float sc = (g == 4) ? LOG2E2 : -LOG2E;
        int n = g * 64 + nb;
#pragma unroll
        for (int ks = 0; ks < 4; ++ks) {
            f16x8 v;
            int kb = ks * 32 + q * 8;
#pragma unroll
            for (int j = 0; j < 8; ++j)
                v[j] = (f16)(sc * U[(d * 128 + kb + j) * 320 + n]);
            bf[g][ks] = v;
        }
        f16x8 v5 = {(f16)0, (f16)0, (f16)0, (f16)0, (f16)0, (f16)0, (f16)0, (f16)0};
        if (q == 0) {
            v5[0] = (f16)(sc * Wx[d * 320 + n]);
            v5[1] = (f16)(sc * bias[d * 320 + n]);
        }
        bf[g][4] = v5;
    }
    __syncthreads();   // zero-init complete

    // ones in the x-region ([65]=1) of every slot, both buffers; seed x(0,0)
    if (tid < 2 * BT * NSLOT) {
        int buf = tid / (BT * NSLOT), rem = tid % (BT * NSLOT);
        int b = rem / NSLOT, sl = rem % NSLOT;
        Fh[buf][b][sl * S_H + 65] = (f16)1.0f;
    }
    if (tid < BT) Fh[0][tid][27 * S_H + 64] = (f16)xs[0][0][tid];
    __syncthreads();

    // one anti-diagonal; br is a literal at every callsite -> const-folds
    auto step = [&](int t, int br) __attribute__((always_inline)) {
        const int bw  = br ^ 1;
        const int rlo = (t > GRIDN - 1) ? (t - (GRIDN - 1)) : 0;
        const int rhi = (t < GRIDN - 1) ? t : (GRIDN - 1);
        const int k   = rhi - rlo + 1;
        const int nM  = (2 * k + 15) >> 4;

        // stage x for diagonal t+1 into the write buffer (tail lanes of last wave)
        if (t < 2 * GRIDN - 2 && tid >= NTHR - 56) {
            int idx = tid - (NTHR - 56), b = idx & 1, j = idx >> 1;
            int rlo2 = (t + 1 > GRIDN - 1) ? (t + 1 - (GRIDN - 1)) : 0;
            int rhi2 = (t + 1 < GRIDN - 1) ? (t + 1) : (GRIDN - 1);
            if (j <= rhi2 - rlo2) {
                int r = rlo2 + j;
                Fh[bw][b][(27 - r) * S_H + 64] = (f16)xs[r][t + 1 - r][b];
            }
        }

        for (int mt = wm; mt < nM; mt += 2) {
            // ---- A fragments: task row mA -> (batch bA, grid row rA)
            int mA = mt * 16 + l16;
            int jA = mA >> 1; if (jA > k - 1) jA = k - 1;
            int bA = mA & 1;
            int slA = 27 - (rlo + jA);
            const f16* ab = &Fh[br][bA][slA * S_H];
            f16x8 a0 = *(const f16x8*)(ab + q * 8);              // h_left k 0..63
            f16x8 a1 = *(const f16x8*)(ab + 32 + q * 8);
            f16x8 a2 = *(const f16x8*)(ab + S_H + q * 8);        // h_up   k 64..127
            f16x8 a3 = *(const f16x8*)(ab + S_H + 32 + q * 8);
            f16x8 a4 = *(const f16x8*)(ab + 64 + q * 8);         // {x,1,0..} k 128..159

            // ---- epilogue addresses + c-state PRELOAD (LDS latency drains
            // under the MFMA block)
            int j0  = mt * 8 + q * 2;
            int jj0 = (j0     > k - 1) ? k - 1 : j0;
            int jj1 = (j0 + 1 > k - 1) ? k - 1 : j0 + 1;
            int sl0 = 27 - (rlo + jj0);
            int sl1 = 27 - (rlo + jj1);
            const float* rp[4] = { &Fc[br][0][sl0 * S_C + nb], &Fc[br][1][sl0 * S_C + nb],
                                   &Fc[br][0][sl1 * S_C + nb], &Fc[br][1][sl1 * S_C + nb] };
            float pcl[4], pcu[4];
#pragma unroll
            for (int i = 0; i < 4; ++i) { pcl[i] = rp[i][0]; pcu[i] = rp[i][S_C]; }

            // ---- MFMA: two independent chains per gate (depth 5 -> 3)
            const f32x4 z4 = {0.f, 0.f, 0.f, 0.f};
            f32x4 accP[5], accQ[5];
#pragma unroll
            for (int g = 0; g < 5; ++g) accP[g] = __builtin_amdgcn_mfma_f32_16x16x32_f16(a4, bf[g][4], z4, 0, 0, 0);
#pragma unroll
            for (int g = 0; g < 5; ++g) accQ[g] = __builtin_amdgcn_mfma_f32_16x16x32_f16(a2, bf[g][2], z4, 0, 0, 0);
#pragma unroll
            for (int g = 0; g < 5; ++g) accP[g] = __builtin_amdgcn_mfma_f32_16x16x32_f16(a0, bf[g][0], accP[g], 0, 0, 0);
#pragma unroll
            for (int g = 0; g < 5; ++g) accQ[g] = __builtin_amdgcn_mfma_f32_16x16x32_f16(a3, bf[g][3], accQ[g], 0, 0, 0);
#pragma unroll
            for (int g = 0; g < 5; ++g) accP[g] = __builtin_amdgcn_mfma_f32_16x16x32_f16(a1, bf[g][1], accP[g], 0, 0, 0);
            f32x4 acc[5];
#pragma unroll
            for (int g = 0; g < 5; ++g) acc[g] = accP[g] + accQ[g];

            // ---- gates + state, BRANCHLESS, trans-merged (+ cn<=22 clamp:
            // tanh(22)==1.0f exactly; prevents te=inf -> inf*0=NaN).
            const int DC = (bw - br) * (BT * NSLOT * S_C);   // compile-time
            int ih0 = sl0 * S_H + nb, ih1 = sl1 * S_H + nb;
            f16* wh0 = &Fh[bw][0][0];
            f16* wh1 = &Fh[bw][1][0];
#pragma unroll
            for (int i = 0; i < 4; ++i) {
                float ta = 1.0f + ex2(acc[0][i]);
                float tp = 1.0f + ex2(acc[1][i]);
                float tq = 1.0f + ex2(acc[2][i]);
                float td = 1.0f + ex2(acc[3][i]);
                float tb = 1.0f + ex2(acc[4][i]);
                float cn = (tb - 2.0f) * rcpf(ta * tb)
                         + (pcl[i] * tq + pcu[i] * tp) * rcpf(tp * tq);
                float cnc = fminf(cn, 22.0f);
                float te = 1.0f + ex2(LOG2E2 * cnc);
                float hn = (te - 2.0f) * rcpf(td * te);
                *(float*)(rp[i] + DC) = cn;
                ((i & 1) ? wh1 : wh0)[(i < 2) ? ih0 : ih1] = (f16)hn;
            }
        }
        __syncthreads();
    };

    for (int tb = 0; tb < 27; ++tb) { step(2 * tb, 0); step(2 * tb + 1, 1); }
    step(54, 0);

    // final h(27,27): t=54 wrote buf 1, slot 0
    if (tid < BT * HID) {
        int bl = tid >> 6, h = tid & 63;
        Hout[(d * BATCH + tile * BT + bl) * HID + h] = (float)Fh[1][bl][h];
    }
    __syncthreads();   // all H stores issued (WG-wide)

    // ---- fused FC head: the 4th dir-WG of this batch-pair runs it --------
    if (fused) {
        if (tid == 0) {
            __threadfence();                       // release our H writes
            unsigned my  = 1u << (2 * d);          // bits 0/2/4/6: clear in 0xAA poison
            unsigned old = atomicOr(&cnt[tile], my);
            fcflag = (((old | my) & 0x55u) == 0x55u) ? 1 : 0;
        }
        __syncthreads();
        if (fcflag) {
            __threadfence();                       // acquire the other 3 WGs' H
            {   // load both rows' [4*64] h
                int r = tid >> 8, idx = tid & 255;
                hrow2[r][idx] = Hout[(idx >> 6) * (BATCH * HID)
                                     + (tile * BT + r) * HID + (idx & 63)];
            }
            __syncthreads();
            {   // z1 = relu(h @ W1 + b1), one col per thread, both rows
                float s0 = b1[tid], s1 = s0;
#pragma unroll 8
                for (int f = 0; f < NDIR * HID; ++f) {
                    float w = W1[f * FC_HD + tid];
                    s0 += hrow2[0][f] * w;
                    s1 += hrow2[1][f] * w;
                }
                z1b[0][tid] = fmaxf(s0, 0.0f);
                z1b[1][tid] = fmaxf(s1, 0.0f);
            }
            __syncthreads();
            {   // z2 partials: 32 slices x 16 cols (10 used), both rows
                int sl = tid >> 4, j = tid & 15;
                float p0 = 0.0f, p1 = 0.0f;
                if (j < OUT_N) {
#pragma unroll
                    for (int i = 0; i < 16; ++i) {
                        int kk = sl * 16 + i;
                        float w = W2[kk * OUT_N + j];
                        p0 += z1b[0][kk] * w;
                        p1 += z1b[1][kk] * w;
                    }
                }
                ps2[0][sl][j] = p0;
                ps2[1][sl][j] = p1;
            }
            __syncthreads();
            if (tid < 32) {
                int r = tid >> 4, j = tid & 15;
                if (j < OUT_N) {
                    float s = b2[j];
#pragma unroll
                    for (int sl = 0; sl < 32; ++sl) s += ps2[r][sl][j];
                    z2b[r][j] = s;
                }
            }
            __syncthreads();
            if (tid < 2) {
                int r = tid;
                float m = z2b[r][0];
                for (int j = 1; j < OUT_N; ++j) m = fmaxf(m, z2b[r][j]);
                float sum = 0.0f, e[OUT_N];
                for (int j = 0; j < OUT_N; ++j) { e[j] = __expf(z2b[r][j] - m); sum += e[j]; }
                float inv = 1.0f / sum;
                for (int j = 0; j < OUT_N; ++j)
                    out[(tile * BT + r) * OUT_N + j] = e[j] * inv;
            }
        }
    }
}

// Fallback FC head (only launched if ws_size can't hold the counters).
__global__ __launch_bounds__(256)
void fc_kernel(const float* __restrict__ Hin,  // [4][B][64]
               const float* __restrict__ W1, const float* __restrict__ b1,
               const float* __restrict__ W2, const float* __restrict__ b2,
               float* __restrict__ out)        // [B][10]
{
    const int b   = blockIdx.x;
    const int tid = threadIdx.x;
    __shared__ float hrow[NDIR * HID];
    __shared__ float z1[FC_HD];
    __shared__ float ps[16][16];
    __shared__ float z2[16];

    hrow[tid] = Hin[(tid >> 6) * (BATCH * HID) + b * HID + (tid & 63)];
    __syncthreads();
    {
        float s0 = b1[tid], s1 = b1[tid + 256];
#pragma unroll 8
        for (int f = 0; f < NDIR * HID; ++f) {
            float h = hrow[f];
            s0 += h * W1[f * FC_HD + tid];
            s1 += h * W1[f * FC_HD + tid + 256];
        }
        z1[tid]       = fmaxf(s0, 0.0f);
        z1[tid + 256] = fmaxf(s1, 0.0f);
    }
    __syncthreads();
    {
        int j = tid & 15, sl = tid >> 4;
        float s = 0.0f;
        if (j < OUT_N) {
#pragma unroll
            for (int i = 0; i < 32; ++i) {
                int kk = sl * 32 + i;
                s += z1[kk] * W2[kk * OUT_N + j];
            }
        }
        ps[sl][j] = s;
    }
    __syncthreads();
    if (tid < OUT_N) {
        float s = b2[tid];
#pragma unroll
        for (int sl = 0; sl < 16; ++sl) s += ps[sl][tid];
        z2[tid] = s;
    }
    __syncthreads();
    if (tid == 0) {
        float m = z2[0];
        for (int j = 1; j < OUT_N; ++j) m = fmaxf(m, z2[j]);
        float sum = 0.0f, e[OUT_N];
        for (int j = 0; j < OUT_N; ++j) { e[j] = __expf(z2[j] - m); sum += e[j]; }
        float inv = 1.0f / sum;
        for (int j = 0; j < OUT_N; ++j) out[b * OUT_N + j] = e[j] * inv;
    }
}

extern "C" void kernel_launch(void* const* d_in, const int* in_sizes, int n_in,
                              void* d_out, int out_size, void* d_ws, size_t ws_size,
                              hipStream_t stream) {
    const float* x  = (const float*)d_in[0];
    const float* Wx = (const float*)d_in[1];
    const float* U  = (const float*)d_in[2];
    const float* bs = (const float*)d_in[3];
    const float* W1 = (const float*)d_in[4];
    const float* b1 = (const float*)d_in[5];
    const float* W2 = (const float*)d_in[6];
    const float* b2 = (const float*)d_in[7];
    float* out = (float*)d_out;
    float* Hws = (float*)d_ws;                 // [4][128][64] fp32 = 131072 B
    const size_t HBYTES = (size_t)NDIR * BATCH * HID * sizeof(float);
    unsigned* cnt = (unsigned*)((char*)d_ws + HBYTES);   // 64 x u32
    const int fused = (ws_size >= HBYTES + 64 * sizeof(unsigned)) ? 1 : 0;

    mdlstm_kernel<<<NDIR * (BATCH / BT), NTHR, 0, stream>>>(
        x, Wx, U, bs, Hws, W1, b1, W2, b2, out, cnt, fused);
    if (!fused)
        fc_kernel<<<BATCH, 256, 0, stream>>>(Hws, W1, b1, W2, b2, out);
}

// Round 15
// 153.243 us; speedup vs baseline: 1.1692x; 1.1692x over previous
//
#include <hip/hip_runtime.h>
#include <hip/hip_bf16.h>

// 2D-MDLSTM (4 directions) + FC head for MI355X — round 15 (= R12 verbatim).
//
// R14 post-mortem: fc fusion + MFMA chain split cut the launch gap by ~23 us
// but cost +48 us in-kernel (MfmaUtil 25->16, long low-occupancy tail) —
// net regression; both reverted.
//
// R12 is the measured optimum (153.8 us total / 83.1 us mdlstm). The kernel
// is DEPENDENCY-bound (55 serial anti-diagonal barriers), not pipe-bound:
// HBM 0.25% peak, MFMA 25%, VALU 55%. Falsified levers: more waves/WG
// (R6-8 spill), co-resident WGs (R5/R10), intra-wave ILP (R13), fusion (R14).
//
// Structure: 256 WGs (4 dir x 64 batch-pairs) x 512 thr; per-WG register-
// resident gate-scaled U fragments (exp2-folded); x*Wx+b as 5th MFMA
// K-step; double-buffered LDS frontier (S_H=104/S_C=68 padding); c-preload
// before the MFMA block; merged transcendentals with cn<=22 clamp
// (tanh(22)==1.0f exactly — prevents inf*0=NaN on accumulated c);
// t-loop x2 unrolled so buffer indices const-fold; branchless clamped
// epilogue (padding rows duplicate same-wave same-value writes).

#define GRIDN 28
#define BATCH 128
#define HID   64
#define NDIR  4
#define FC_HD 512
#define OUT_N 10
#define BT    2
#define NTHR  512
#define NSLOT 29          // 28 frontier rows + permanent-zero row (r = -1)
#define S_H   104         // f16/slot: [0,64) h | [64]=x [65]=1 [66,96)=0 | 8 pad
#define S_C   68          // float/slot: 64 c + 4 pad

typedef _Float16 f16;
typedef _Float16 f16x8 __attribute__((ext_vector_type(8)));
typedef float    f32x4 __attribute__((ext_vector_type(4)));

#define LOG2E  1.44269504088896340736f
#define LOG2E2 2.88539008177792681472f

__device__ __forceinline__ float rcpf(float x) { return __builtin_amdgcn_rcpf(x); }
__device__ __forceinline__ float ex2(float x)  { return __builtin_amdgcn_exp2f(x); }

__global__ __launch_bounds__(NTHR)
void mdlstm_kernel(const float* __restrict__ x,    // [B][28][28]
                   const float* __restrict__ Wx,   // [4][320]
                   const float* __restrict__ U,    // [4][128][320]
                   const float* __restrict__ bias, // [4][320]
                   float* __restrict__ Hout)       // [4][B][64]
{
    const int d    = blockIdx.x & 3;
    const int tile = blockIdx.x >> 2;     // 0..63 batch-pair
    const int tid  = threadIdx.x;
    const int lane = tid & 63;
    const int wave = tid >> 6;            // 0..7
    const int wm   = wave >> 2;           // tile parity 0/1
    const int wh   = wave & 3;            // h-subtile (n = wh*16 + l16)
    const int l16  = lane & 15;
    const int q    = lane >> 4;
    const int nb   = wh * 16 + l16;       // this lane's h index 0..63

    __shared__ __align__(16) f16 Fh[2][BT][NSLOT * S_H];
    __shared__ float             Fc[2][BT][NSLOT * S_C];
    __shared__ float             xs[GRIDN][GRIDN][BT];

    for (int i = tid; i < 2 * BT * NSLOT * S_H; i += NTHR) ((f16*)Fh)[i] = (f16)0.0f;
    for (int i = tid; i < 2 * BT * NSLOT * S_C; i += NTHR) ((float*)Fc)[i] = 0.0f;
    for (int i = tid; i < GRIDN * GRIDN * BT; i += NTHR) {
        int bl = i & 1, rc = i >> 1, c = rc % GRIDN, r = rc / GRIDN;
        int rr = (d & 2) ? (GRIDN - 1 - r) : r;
        int cc = (d & 1) ? (GRIDN - 1 - c) : c;
        xs[r][c][bl] = x[((tile * BT + bl) * GRIDN + rr) * GRIDN + cc];
    }

    // ---- B-fragments in registers, gate-scaled: 25 x f16x8 (100 regs)
    // sigmoid gates scaled by -log2e (sig = rcp(1+2^acc)); g gate by +2log2e.
    f16x8 bf[5][5];
#pragma unroll
    for (int g = 0; g < 5; ++g) {
        const float sc = (g == 4) ? LOG2E2 : -LOG2E;
        int n = g * 64 + nb;
#pragma unroll
        for (int ks = 0; ks < 4; ++ks) {
            f16x8 v;
            int kb = ks * 32 + q * 8;
#pragma unroll
            for (int j = 0; j < 8; ++j)
                v[j] = (f16)(sc * U[(d * 128 + kb + j) * 320 + n]);
            bf[g][ks] = v;
        }
        f16x8 v5 = {(f16)0, (f16)0, (f16)0, (f16)0, (f16)0, (f16)0, (f16)0, (f16)0};
        if (q == 0) {
            v5[0] = (f16)(sc * Wx[d * 320 + n]);
            v5[1] = (f16)(sc * bias[d * 320 + n]);
        }
        bf[g][4] = v5;
    }
    __syncthreads();   // zero-init complete

    // ones in the x-region ([65]=1) of every slot, both buffers; seed x(0,0)
    if (tid < 2 * BT * NSLOT) {
        int buf = tid / (BT * NSLOT), rem = tid % (BT * NSLOT);
        int b = rem / NSLOT, sl = rem % NSLOT;
        Fh[buf][b][sl * S_H + 65] = (f16)1.0f;
    }
    if (tid < BT) Fh[0][tid][27 * S_H + 64] = (f16)xs[0][0][tid];
    __syncthreads();

    // one anti-diagonal; br is a literal at every callsite -> const-folds
    auto step = [&](int t, int br) __attribute__((always_inline)) {
        const int bw  = br ^ 1;
        const int rlo = (t > GRIDN - 1) ? (t - (GRIDN - 1)) : 0;
        const int rhi = (t < GRIDN - 1) ? t : (GRIDN - 1);
        const int k   = rhi - rlo + 1;
        const int nM  = (2 * k + 15) >> 4;

        // stage x for diagonal t+1 into the write buffer (tail lanes of last wave)
        if (t < 2 * GRIDN - 2 && tid >= NTHR - 56) {
            int idx = tid - (NTHR - 56), b = idx & 1, j = idx >> 1;
            int rlo2 = (t + 1 > GRIDN - 1) ? (t + 1 - (GRIDN - 1)) : 0;
            int rhi2 = (t + 1 < GRIDN - 1) ? (t + 1) : (GRIDN - 1);
            if (j <= rhi2 - rlo2) {
                int r = rlo2 + j;
                Fh[bw][b][(27 - r) * S_H + 64] = (f16)xs[r][t + 1 - r][b];
            }
        }

        for (int mt = wm; mt < nM; mt += 2) {
            // ---- A fragments: task row mA -> (batch bA, grid row rA)
            int mA = mt * 16 + l16;
            int jA = mA >> 1; if (jA > k - 1) jA = k - 1;
            int bA = mA & 1;
            int slA = 27 - (rlo + jA);
            const f16* ab = &Fh[br][bA][slA * S_H];
            f16x8 a0 = *(const f16x8*)(ab + q * 8);              // h_left k 0..63
            f16x8 a1 = *(const f16x8*)(ab + 32 + q * 8);
            f16x8 a2 = *(const f16x8*)(ab + S_H + q * 8);        // h_up   k 64..127
            f16x8 a3 = *(const f16x8*)(ab + S_H + 32 + q * 8);
            f16x8 a4 = *(const f16x8*)(ab + 64 + q * 8);         // {x,1,0..} k 128..159

            // ---- epilogue addresses + c-state PRELOAD (before MFMAs: their
            // ~120 cyc LDS latency drains under the MFMA block)
            int j0  = mt * 8 + q * 2;
            int jj0 = (j0     > k - 1) ? k - 1 : j0;
            int jj1 = (j0 + 1 > k - 1) ? k - 1 : j0 + 1;
            int sl0 = 27 - (rlo + jj0);
            int sl1 = 27 - (rlo + jj1);
            const float* rp[4] = { &Fc[br][0][sl0 * S_C + nb], &Fc[br][1][sl0 * S_C + nb],
                                   &Fc[br][0][sl1 * S_C + nb], &Fc[br][1][sl1 * S_C + nb] };
            float pcl[4], pcu[4];
#pragma unroll
            for (int i = 0; i < 4; ++i) { pcl[i] = rp[i][0]; pcu[i] = rp[i][S_C]; }

            const f32x4 z4 = {0.f, 0.f, 0.f, 0.f};               // shared zero-C
            f32x4 acc[5];
#pragma unroll
            for (int g = 0; g < 5; ++g) acc[g] = __builtin_amdgcn_mfma_f32_16x16x32_f16(a4, bf[g][4], z4, 0, 0, 0);
#pragma unroll
            for (int g = 0; g < 5; ++g) acc[g] = __builtin_amdgcn_mfma_f32_16x16x32_f16(a0, bf[g][0], acc[g], 0, 0, 0);
#pragma unroll
            for (int g = 0; g < 5; ++g) acc[g] = __builtin_amdgcn_mfma_f32_16x16x32_f16(a1, bf[g][1], acc[g], 0, 0, 0);
#pragma unroll
            for (int g = 0; g < 5; ++g) acc[g] = __builtin_amdgcn_mfma_f32_16x16x32_f16(a2, bf[g][2], acc[g], 0, 0, 0);
#pragma unroll
            for (int g = 0; g < 5; ++g) acc[g] = __builtin_amdgcn_mfma_f32_16x16x32_f16(a3, bf[g][3], acc[g], 0, 0, 0);

            // ---- gates + state, BRANCHLESS, trans-merged.
            // acc0=-log2e*i  acc1=-log2e*f1  acc2=-log2e*f2  acc3=-log2e*o
            // acc4=+2log2e*g
            //   sig(i)*tanh(g)        = (tb-2)*rcp(ta*tb)
            //   sig(f1)*cl+sig(f2)*cu = (cl*tq+cu*tp)*rcp(tp*tq)
            //   sig(o)*tanh(cn)       = (te-2)*rcp(td*te), cn clamped to 22
            //     for te only (tanh(22)==1.0f exactly; prevents te=inf ->
            //     inf*0=NaN when the accumulated c exceeds 44 — the R11 bug).
            const int DC = (bw - br) * (BT * NSLOT * S_C);   // compile-time
            int ih0 = sl0 * S_H + nb, ih1 = sl1 * S_H + nb;
            f16* wh0 = &Fh[bw][0][0];
            f16* wh1 = &Fh[bw][1][0];
#pragma unroll
            for (int i = 0; i < 4; ++i) {
                float ta = 1.0f + ex2(acc[0][i]);
                float tp = 1.0f + ex2(acc[1][i]);
                float tq = 1.0f + ex2(acc[2][i]);
                float td = 1.0f + ex2(acc[3][i]);
                float tb = 1.0f + ex2(acc[4][i]);
                float cn = (tb - 2.0f) * rcpf(ta * tb)
                         + (pcl[i] * tq + pcu[i] * tp) * rcpf(tp * tq);
                float cnc = fminf(cn, 22.0f);
                float te = 1.0f + ex2(LOG2E2 * cnc);
                float hn = (te - 2.0f) * rcpf(td * te);
                *(float*)(rp[i] + DC) = cn;
                ((i & 1) ? wh1 : wh0)[(i < 2) ? ih0 : ih1] = (f16)hn;
            }
        }
        __syncthreads();
    };

    for (int tb = 0; tb < 27; ++tb) { step(2 * tb, 0); step(2 * tb + 1, 1); }
    step(54, 0);

    // final h(27,27): t=54 wrote buf 1, slot 0
    if (tid < BT * HID) {
        int bl = tid >> 6, h = tid & 63;
        Hout[(d * BATCH + tile * BT + bl) * HID + h] = (float)Fh[1][bl][h];
    }
}

// FC head, one WG per batch row. z1 (512 cols) by 256 threads x 2 cols with
// coalesced W1 reads; z2 via 16-slice x 16-col partials + LDS reduce;
// softmax over 10 by one thread.
__global__ __launch_bounds__(256)
void fc_kernel(const float* __restrict__ Hin,  // [4][B][64]
               const float* __restrict__ W1, const float* __restrict__ b1,
               const float* __restrict__ W2, const float* __restrict__ b2,
               float* __restrict__ out)        // [B][10]
{
    const int b   = blockIdx.x;
    const int tid = threadIdx.x;
    __shared__ float hrow[NDIR * HID];
    __shared__ float z1[FC_HD];
    __shared__ float ps[16][16];
    __shared__ float z2[16];

    hrow[tid] = Hin[(tid >> 6) * (BATCH * HID) + b * HID + (tid & 63)];
    __syncthreads();

    // ---- z1 = relu(hrow @ W1 + b1): each thread cols {tid, tid+256}
    {
        float s0 = b1[tid], s1 = b1[tid + 256];
#pragma unroll 8
        for (int f = 0; f < NDIR * HID; ++f) {
            float h = hrow[f];
            s0 += h * W1[f * FC_HD + tid];
            s1 += h * W1[f * FC_HD + tid + 256];
        }
        z1[tid]       = fmaxf(s0, 0.0f);
        z1[tid + 256] = fmaxf(s1, 0.0f);
    }
    __syncthreads();

    // ---- z2 partials: j = tid&15 (10 used), slice = tid>>4 covers 32 k each
    {
        int j = tid & 15, sl = tid >> 4;
        float s = 0.0f;
        if (j < OUT_N) {
#pragma unroll
            for (int i = 0; i < 32; ++i) {
                int kk = sl * 32 + i;
                s += z1[kk] * W2[kk * OUT_N + j];
            }
        }
        ps[sl][j] = s;
    }
    __syncthreads();

    if (tid < OUT_N) {
        float s = b2[tid];
#pragma unroll
        for (int sl = 0; sl < 16; ++sl) s += ps[sl][tid];
        z2[tid] = s;
    }
    __syncthreads();

    if (tid == 0) {
        float m = z2[0];
        for (int j = 1; j < OUT_N; ++j) m = fmaxf(m, z2[j]);
        float sum = 0.0f, e[OUT_N];
        for (int j = 0; j < OUT_N; ++j) { e[j] = __expf(z2[j] - m); sum += e[j]; }
        float inv = 1.0f / sum;
        for (int j = 0; j < OUT_N; ++j) out[b * OUT_N + j] = e[j] * inv;
    }
}

extern "C" void kernel_launch(void* const* d_in, const int* in_sizes, int n_in,
                              void* d_out, int out_size, void* d_ws, size_t ws_size,
                              hipStream_t stream) {
    const float* x  = (const float*)d_in[0];
    const float* Wx = (const float*)d_in[1];
    const float* U  = (const float*)d_in[2];
    const float* bs = (const float*)d_in[3];
    const float* W1 = (const float*)d_in[4];
    const float* b1 = (const float*)d_in[5];
    const float* W2 = (const float*)d_in[6];
    const float* b2 = (const float*)d_in[7];
    float* out = (float*)d_out;
    float* Hws = (float*)d_ws;   // [4][128][64] fp32 = 128 KiB

    mdlstm_kernel<<<NDIR * (BATCH / BT), NTHR, 0, stream>>>(x, Wx, U, bs, Hws);
    fc_kernel<<<BATCH, 256, 0, stream>>>(Hws, W1, b1, W2, b2, out);
}